// Round 4
// baseline (392.441 us; speedup 1.0000x reference)
//
#include <hip/hip_runtime.h>
#include <hip/hip_fp16.h>
#include <math.h>

#define NNODES 50000
#define NEDGES 1600000
#define HID 128
#define NH (NNODES * HID)          // 6,400,000
#define CAP 112                    // max in-degree (Poisson(32): P(>=112) ~ 1e-22)
#define NBINS 196                  // dest bins of 256 nodes (bin = c >> 8)
#define BCAP 9216                  // edges per bin: mean 8163, +11 sigma
#define BIN_BLOCKS 250
#define EPB (NEDGES / BIN_BLOCKS)  // 6400
#define SCALE 0.17677669529663687f // 1/sqrt(32)

__global__ void k_init(int* __restrict__ binCnt, float* __restrict__ den_part) {
    int idx = blockIdx.x * blockDim.x + threadIdx.x;
    if (idx < NBINS) binCnt[idx] = 0;
    if (idx < 256) den_part[idx] = 0.f;
}

// Q/K/V projection -> fp16; one thread per (node, 2 cols)
__global__ void k_qkv(const float* __restrict__ x,
                      const float* __restrict__ Wq, const float* __restrict__ bq,
                      const float* __restrict__ Wk, const float* __restrict__ bk,
                      const float* __restrict__ Wv, const float* __restrict__ bv,
                      __half* __restrict__ Qh, __half* __restrict__ Kh,
                      __half* __restrict__ Vh) {
    int idx = blockIdx.x * blockDim.x + threadIdx.x;
    if (idx >= NH / 2) return;
    int i = idx >> 6;
    int j = (idx & 63) * 2;
    float4 xv = ((const float4*)x)[i];
    float4 a, b;
    a = ((const float4*)Wq)[j]; b = ((const float4*)Wq)[j + 1];
    float q0 = xv.x * a.x + xv.y * a.y + xv.z * a.z + xv.w * a.w + bq[j];
    float q1 = xv.x * b.x + xv.y * b.y + xv.z * b.z + xv.w * b.w + bq[j + 1];
    ((__half2*)Qh)[idx] = __floats2half2_rn(q0, q1);
    a = ((const float4*)Wk)[j]; b = ((const float4*)Wk)[j + 1];
    float k0 = xv.x * a.x + xv.y * a.y + xv.z * a.z + xv.w * a.w + bk[j];
    float k1 = xv.x * b.x + xv.y * b.y + xv.z * b.z + xv.w * b.w + bk[j + 1];
    ((__half2*)Kh)[idx] = __floats2half2_rn(k0, k1);
    a = ((const float4*)Wv)[j]; b = ((const float4*)Wv)[j + 1];
    float v0 = xv.x * a.x + xv.y * a.y + xv.z * a.z + xv.w * a.w + bv[j];
    float v1 = xv.x * b.x + xv.y * b.y + xv.z * b.z + xv.w * b.w + bv[j + 1];
    ((__half2*)Vh)[idx] = __floats2half2_rn(v0, v1);
}

// Pass A: bin edges by dest range (256 nodes/bin). LDS histogram + one global
// reserve per (block,bin) -> packed (c<<16)|r written in short contiguous runs.
__global__ void k_binA(const int* __restrict__ ei, int* __restrict__ binCnt,
                       unsigned* __restrict__ binned) {
    __shared__ int hist[NBINS];
    __shared__ int resv[NBINS];
    int t = threadIdx.x;
    for (int i = t; i < NBINS; i += 256) hist[i] = 0;
    __syncthreads();
    int e0 = blockIdx.x * EPB;
    for (int i = t; i < EPB; i += 256) {
        int c = ei[NEDGES + e0 + i];
        atomicAdd(&hist[c >> 8], 1);
    }
    __syncthreads();
    for (int i = t; i < NBINS; i += 256) {
        resv[i] = atomicAdd(&binCnt[i], hist[i]);
        hist[i] = 0;
    }
    __syncthreads();
    for (int i = t; i < EPB; i += 256) {
        int e = e0 + i;
        int r = ei[e];
        int c = ei[NEDGES + e];
        int b = c >> 8;
        int off = resv[b] + atomicAdd(&hist[b], 1);
        if (off < BCAP) binned[b * BCAP + off] = ((unsigned)c << 16) | (unsigned)r;
    }
}

// Pass B: one block OWNS one bin -> all perm writes stay in one XCD's L2.
__global__ void k_fillB(const unsigned* __restrict__ binned,
                        const int* __restrict__ binCnt,
                        unsigned short* __restrict__ perm, int* __restrict__ cnt) {
    __shared__ int lcnt[256];
    int b = blockIdx.x;
    int t = threadIdx.x;
    lcnt[t] = 0;
    __syncthreads();
    int n = binCnt[b]; if (n > BCAP) n = BCAP;
    int base = b << 8;
    for (int i = t; i < n; i += 256) {
        unsigned v = binned[b * BCAP + i];
        int c = v >> 16;
        int r = v & 0xFFFF;
        int slot = atomicAdd(&lcnt[c - base], 1);
        if (slot < CAP) perm[c * CAP + slot] = (unsigned short)r;
    }
    __syncthreads();
    int node = base + t;
    if (node < NNODES) cnt[node] = lcnt[t] < CAP ? lcnt[t] : CAP;
}

// Fused score + exp + raw accumulate (normalization deferred to k_out since
// the softmax denominator is global per head). One block per dest node.
// 8 edge-groups of 32 lanes; lane owns dims [lane*4, lane*4+4), head = lane>>3.
__global__ void k_fused(const unsigned short* __restrict__ perm,
                        const int* __restrict__ cnt,
                        const __half* __restrict__ Qh, const __half* __restrict__ Kh,
                        const __half* __restrict__ Vh,
                        float* __restrict__ att_raw, float* __restrict__ den_part) {
    int node = blockIdx.x;
    int tid = threadIdx.x;   // 0..255
    int lane = tid & 31;
    int grp = tid >> 5;      // 0..7
    int sub = lane & 7;
    __shared__ float lds_att[HID];
    __shared__ float sd[4];
    if (tid < HID) lds_att[tid] = 0.f;
    if (tid >= HID && tid < HID + 4) sd[tid - HID] = 0.f;
    __syncthreads();
    int deg = cnt[node];
    uint2 ku = *(const uint2*)(Kh + node * HID + lane * 4);
    float2 kf0 = __half22float2(*(__half2*)&ku.x);
    float2 kf1 = __half22float2(*(__half2*)&ku.y);
    float4 acc = {0.f, 0.f, 0.f, 0.f};
    float lsum = 0.f;
    for (int s = grp; s < deg; s += 8) {
        int r = perm[node * CAP + s];
        uint2 qu = *(const uint2*)(Qh + r * HID + lane * 4);
        float2 q0 = __half22float2(*(__half2*)&qu.x);
        float2 q1 = __half22float2(*(__half2*)&qu.y);
        float d = q0.x * kf0.x + q0.y * kf0.y + q1.x * kf1.x + q1.y * kf1.y;
        d += __shfl_xor(d, 1);
        d += __shfl_xor(d, 2);
        d += __shfl_xor(d, 4);
        float p = __expf(d * SCALE);
        uint2 vu = *(const uint2*)(Vh + r * HID + lane * 4);
        float2 v0 = __half22float2(*(__half2*)&vu.x);
        float2 v1 = __half22float2(*(__half2*)&vu.y);
        acc.x += p * v0.x; acc.y += p * v0.y;
        acc.z += p * v1.x; acc.w += p * v1.y;
        if (sub == 0) lsum += p;
    }
    atomicAdd(&lds_att[lane * 4 + 0], acc.x);
    atomicAdd(&lds_att[lane * 4 + 1], acc.y);
    atomicAdd(&lds_att[lane * 4 + 2], acc.z);
    atomicAdd(&lds_att[lane * 4 + 3], acc.w);
    if (sub == 0) atomicAdd(&sd[lane >> 3], lsum);
    __syncthreads();
    if (tid < HID) att_raw[node * HID + tid] = lds_att[tid];
    if (tid < 4) atomicAdd(&den_part[(node & 63) * 4 + tid], sd[tid]);
}

__global__ void k_fin(const float* __restrict__ den_part, float* __restrict__ dinv) {
    int t = threadIdx.x;
    if (t < 4) {
        float s = 0.f;
        for (int i = 0; i < 64; i++) s += den_part[i * 4 + t];
        dinv[t] = 1.f / s;
    }
}

// normalize + output projection + residual; one thread per node
__global__ void k_out(const float* __restrict__ att_raw, const float* __restrict__ dinv,
                      const float* __restrict__ Wo, const float* __restrict__ bo,
                      const float* __restrict__ x, float* __restrict__ out) {
    int i = blockIdx.x * blockDim.x + threadIdx.x;
    if (i >= NNODES) return;
    float di0 = dinv[0], di1 = dinv[1], di2 = dinv[2], di3 = dinv[3];
    float a0 = bo[0], a1 = bo[1], a2 = bo[2], a3 = bo[3];
    const float4* ar = (const float4*)(att_raw + i * HID);
#pragma unroll 8
    for (int j4 = 0; j4 < HID / 4; j4++) {
        float4 av = ar[j4];
        float dh = (j4 < 8) ? di0 : (j4 < 16) ? di1 : (j4 < 24) ? di2 : di3;
        int j = j4 * 4;
        a0 += dh * (av.x * Wo[j] + av.y * Wo[j + 1] + av.z * Wo[j + 2] + av.w * Wo[j + 3]);
        a1 += dh * (av.x * Wo[HID + j] + av.y * Wo[HID + j + 1] + av.z * Wo[HID + j + 2] + av.w * Wo[HID + j + 3]);
        a2 += dh * (av.x * Wo[2 * HID + j] + av.y * Wo[2 * HID + j + 1] + av.z * Wo[2 * HID + j + 2] + av.w * Wo[2 * HID + j + 3]);
        a3 += dh * (av.x * Wo[3 * HID + j] + av.y * Wo[3 * HID + j + 1] + av.z * Wo[3 * HID + j + 2] + av.w * Wo[3 * HID + j + 3]);
    }
    float4 xv = ((const float4*)x)[i];
    float4 o;
    o.x = a0 + xv.x; o.y = a1 + xv.y; o.z = a2 + xv.z; o.w = a3 + xv.w;
    ((float4*)out)[i] = o;
}

extern "C" void kernel_launch(void* const* d_in, const int* in_sizes, int n_in,
                              void* d_out, int out_size, void* d_ws, size_t ws_size,
                              hipStream_t stream) {
    const float* x = (const float*)d_in[0];
    const int* ei = (const int*)d_in[1];
    const float* Wq = (const float*)d_in[2];
    const float* bq = (const float*)d_in[3];
    const float* Wk = (const float*)d_in[4];
    const float* bk = (const float*)d_in[5];
    const float* Wv = (const float*)d_in[6];
    const float* bv = (const float*)d_in[7];
    const float* Wo = (const float*)d_in[8];
    const float* bo = (const float*)d_in[9];
    float* out = (float*)d_out;

    char* ws = (char*)d_ws;
    __half* Qh = (__half*)ws;                        // 12.8 MB
    __half* Kh = Qh + NH;                            // 12.8 MB
    __half* Vh = Kh + NH;                            // 12.8 MB
    float* att_raw = (float*)(Vh + NH);              // 25.6 MB
    unsigned* binned = (unsigned*)(att_raw + NH);    // NBINS*BCAP u32, 7.2 MB
    int* binCnt = (int*)(binned + (size_t)NBINS * BCAP);
    int* cnt = binCnt + NBINS;                       // NNODES
    float* den_part = (float*)(cnt + NNODES);        // 256
    float* dinv = den_part + 256;                    // 4
    unsigned short* perm = (unsigned short*)(dinv + 4);  // NNODES*CAP u16, 11.2 MB

    k_init<<<1, 256, 0, stream>>>(binCnt, den_part);
    k_qkv<<<(NH / 2 + 255) / 256, 256, 0, stream>>>(x, Wq, bq, Wk, bk, Wv, bv, Qh, Kh, Vh);
    k_binA<<<BIN_BLOCKS, 256, 0, stream>>>(ei, binCnt, binned);
    k_fillB<<<NBINS, 256, 0, stream>>>(binned, binCnt, perm, cnt);
    k_fused<<<NNODES, 256, 0, stream>>>(perm, cnt, Qh, Kh, Vh, att_raw, den_part);
    k_fin<<<1, 64, 0, stream>>>(den_part, dinv);
    k_out<<<(NNODES + 255) / 256, 256, 0, stream>>>(att_raw, dinv, Wo, bo, x, out);
}

// Round 5
// 113.835 us; speedup vs baseline: 3.4475x; 3.4475x over previous
//
#include <hip/hip_runtime.h>
#include <math.h>

#define NNODES 50000
#define NEDGES 1600000
#define CAP 112                    // max in-degree (Poisson(32): P(>=112) ~ 1e-22)
#define NBINS 196                  // dest bins of 256 nodes (bin = c >> 8)
#define BCAP 9216                  // edges per bin: mean 8192, +11 sigma
#define BIN_BLOCKS 250
#define EPB (NEDGES / BIN_BLOCKS)  // 6400
#define SCALE 0.17677669529663687f // 1/sqrt(32)

// Constant table C[] layout (192 floats):
//   A[h][a][b]  : 0   + h*16 + a*4 + b   (Wq_h^T Wk_h)
//   U[h][b]     : 64  + h*4 + b          (bq_h^T Wk_h)   pairs with x[c]
//   V[h][a]     : 80  + h*4 + a          (Wq_h^T bk_h)   pairs with x[r]
//   W0[h]       : 96  + h                (bq_h . bk_h)
//   M[h][o][a]  : 100 + h*16 + o*4 + a   (Wo[o,hslice] . Wv_h[:,a])
//   N[h][o]     : 164 + h*4 + o          (Wo[o,hslice] . bv_h)

__global__ void k_setup(const float* __restrict__ Wq, const float* __restrict__ bq,
                        const float* __restrict__ Wk, const float* __restrict__ bk,
                        const float* __restrict__ Wv, const float* __restrict__ bv,
                        const float* __restrict__ Wo,
                        float* __restrict__ C, int* __restrict__ binCnt,
                        float* __restrict__ den) {
    int t = threadIdx.x;
    if (blockIdx.x == 0) {
        if (t < 64) {
            int h = t >> 4, a = (t >> 2) & 3, b = t & 3;
            float s = 0.f;
            for (int k = 0; k < 32; k++) s += Wq[(h * 32 + k) * 4 + a] * Wk[(h * 32 + k) * 4 + b];
            C[t] = s;
        } else if (t < 80) {
            int h = (t - 64) >> 2, b = (t - 64) & 3;
            float s = 0.f;
            for (int k = 0; k < 32; k++) s += bq[h * 32 + k] * Wk[(h * 32 + k) * 4 + b];
            C[t] = s;
        } else if (t < 96) {
            int h = (t - 80) >> 2, a = (t - 80) & 3;
            float s = 0.f;
            for (int k = 0; k < 32; k++) s += Wq[(h * 32 + k) * 4 + a] * bk[h * 32 + k];
            C[t] = s;
        } else if (t < 100) {
            int h = t - 96;
            float s = 0.f;
            for (int k = 0; k < 32; k++) s += bq[h * 32 + k] * bk[h * 32 + k];
            C[t] = s;
        } else if (t < 164) {
            int i = t - 100;
            int h = i >> 4, o = (i >> 2) & 3, a = i & 3;
            float s = 0.f;
            for (int k = 0; k < 32; k++) s += Wo[o * 128 + h * 32 + k] * Wv[(h * 32 + k) * 4 + a];
            C[t] = s;
        } else if (t < 180) {
            int i = t - 164;
            int h = i >> 2, o = i & 3;
            float s = 0.f;
            for (int k = 0; k < 32; k++) s += Wo[o * 128 + h * 32 + k] * bv[h * 32 + k];
            C[t] = s;
        }
    } else {
        if (t < NBINS) binCnt[t] = 0;
        if (t < 4) den[t] = 0.f;
    }
}

// per-node score precompute: g_h[c] = SCALE*(A_h x[c] + V_h), e_h[c] = SCALE*(U_h.x[c] + W0_h)
__global__ void k_proj(const float* __restrict__ x, const float* __restrict__ C,
                       float* __restrict__ proj) {
    int i = blockIdx.x * blockDim.x + threadIdx.x;
    if (i >= NNODES) return;
    float4 xv = ((const float4*)x)[i];
    float pr[20];
#pragma unroll
    for (int h = 0; h < 4; h++) {
#pragma unroll
        for (int a = 0; a < 4; a++) {
            float g = C[80 + h * 4 + a]
                    + C[h * 16 + a * 4 + 0] * xv.x + C[h * 16 + a * 4 + 1] * xv.y
                    + C[h * 16 + a * 4 + 2] * xv.z + C[h * 16 + a * 4 + 3] * xv.w;
            pr[h * 4 + a] = g * SCALE;
        }
        float e = C[96 + h]
                + C[64 + h * 4 + 0] * xv.x + C[64 + h * 4 + 1] * xv.y
                + C[64 + h * 4 + 2] * xv.z + C[64 + h * 4 + 3] * xv.w;
        pr[16 + h] = e * SCALE;
    }
    float4* pp = (float4*)(proj + (size_t)i * 20);
#pragma unroll
    for (int q = 0; q < 5; q++) pp[q] = ((const float4*)pr)[q];
}

// Pass A: bin edges by dest range (256 nodes/bin), packed (c<<16)|r
__global__ void k_binA(const int* __restrict__ ei, int* __restrict__ binCnt,
                       unsigned* __restrict__ binned) {
    __shared__ int hist[NBINS];
    __shared__ int resv[NBINS];
    int t = threadIdx.x;
    for (int i = t; i < NBINS; i += 256) hist[i] = 0;
    __syncthreads();
    int e0 = blockIdx.x * EPB;
    for (int i = t; i < EPB; i += 256) {
        int c = ei[NEDGES + e0 + i];
        atomicAdd(&hist[c >> 8], 1);
    }
    __syncthreads();
    for (int i = t; i < NBINS; i += 256) {
        resv[i] = atomicAdd(&binCnt[i], hist[i]);
        hist[i] = 0;
    }
    __syncthreads();
    for (int i = t; i < EPB; i += 256) {
        int e = e0 + i;
        int r = ei[e];
        int c = ei[NEDGES + e];
        int b = c >> 8;
        int off = resv[b] + atomicAdd(&hist[b], 1);
        if (off < BCAP) binned[b * BCAP + off] = ((unsigned)c << 16) | (unsigned)r;
    }
}

// Pass B: one block owns one bin -> perm writes stay in one L2
__global__ void k_fillB(const unsigned* __restrict__ binned,
                        const int* __restrict__ binCnt,
                        unsigned short* __restrict__ perm, int* __restrict__ cnt) {
    __shared__ int lcnt[256];
    int b = blockIdx.x;
    int t = threadIdx.x;
    lcnt[t] = 0;
    __syncthreads();
    int n = binCnt[b]; if (n > BCAP) n = BCAP;
    int base = b << 8;
    for (int i = t; i < n; i += 256) {
        unsigned v = binned[b * BCAP + i];
        int c = v >> 16;
        int r = v & 0xFFFF;
        int slot = atomicAdd(&lcnt[c - base], 1);
        if (slot < CAP) perm[c * CAP + slot] = (unsigned short)r;
    }
    __syncthreads();
    int node = base + t;
    if (node < NNODES) cnt[node] = lcnt[t] < CAP ? lcnt[t] : CAP;
}

// one THREAD per dest node: gather x[r] (L2-resident, 16B), 4 bilinear scores,
// exp, accumulate rank-4 stats y_h (4 floats/head) and S_h. No Q/K/V arrays.
__global__ void k_accum(const unsigned short* __restrict__ perm,
                        const int* __restrict__ cnt, const float* __restrict__ x,
                        const float* __restrict__ proj, float* __restrict__ acc,
                        float* __restrict__ den) {
    int c = blockIdx.x * blockDim.x + threadIdx.x;
    float S0 = 0.f, S1 = 0.f, S2 = 0.f, S3 = 0.f;
    if (c < NNODES) {
        const float4* pp = (const float4*)(proj + (size_t)c * 20);
        float4 g0 = pp[0], g1 = pp[1], g2 = pp[2], g3 = pp[3], e = pp[4];
        float4 y0 = {0, 0, 0, 0}, y1 = y0, y2 = y0, y3 = y0;
        int deg = cnt[c];
        const unsigned short* pr = perm + (size_t)c * CAP;
#pragma unroll 4
        for (int s = 0; s < deg; s++) {
            int r = pr[s];
            float4 xv = ((const float4*)x)[r];
            float p0 = __expf(xv.x * g0.x + xv.y * g0.y + xv.z * g0.z + xv.w * g0.w + e.x);
            float p1 = __expf(xv.x * g1.x + xv.y * g1.y + xv.z * g1.z + xv.w * g1.w + e.y);
            float p2 = __expf(xv.x * g2.x + xv.y * g2.y + xv.z * g2.z + xv.w * g2.w + e.z);
            float p3 = __expf(xv.x * g3.x + xv.y * g3.y + xv.z * g3.z + xv.w * g3.w + e.w);
            y0.x += p0 * xv.x; y0.y += p0 * xv.y; y0.z += p0 * xv.z; y0.w += p0 * xv.w;
            y1.x += p1 * xv.x; y1.y += p1 * xv.y; y1.z += p1 * xv.z; y1.w += p1 * xv.w;
            y2.x += p2 * xv.x; y2.y += p2 * xv.y; y2.z += p2 * xv.z; y2.w += p2 * xv.w;
            y3.x += p3 * xv.x; y3.y += p3 * xv.y; y3.z += p3 * xv.z; y3.w += p3 * xv.w;
            S0 += p0; S1 += p1; S2 += p2; S3 += p3;
        }
        float4* ap = (float4*)(acc + (size_t)c * 20);
        ap[0] = y0; ap[1] = y1; ap[2] = y2; ap[3] = y3;
        float4 sv = {S0, S1, S2, S3};
        ap[4] = sv;
    }
    // wave-reduce S then one atomic per wave per head
    float t0 = S0, t1 = S1, t2 = S2, t3 = S3;
#pragma unroll
    for (int off = 32; off > 0; off >>= 1) {
        t0 += __shfl_down(t0, off);
        t1 += __shfl_down(t1, off);
        t2 += __shfl_down(t2, off);
        t3 += __shfl_down(t3, off);
    }
    if ((threadIdx.x & 63) == 0) {
        atomicAdd(&den[0], t0);
        atomicAdd(&den[1], t1);
        atomicAdd(&den[2], t2);
        atomicAdd(&den[3], t3);
    }
}

__global__ void k_fin(const float* __restrict__ den, float* __restrict__ dinv) {
    int t = threadIdx.x;
    if (t < 4) dinv[t] = 1.f / den[t];
}

// out[c][o] = sum_h dinv_h*(M_h[o].y_h[c] + S_h[c]*N_h[o]) + bo[o] + x[c][o]
__global__ void k_out(const float* __restrict__ acc, const float* __restrict__ dinv,
                      const float* __restrict__ C, const float* __restrict__ bo,
                      const float* __restrict__ x, float* __restrict__ out) {
    int i = blockIdx.x * blockDim.x + threadIdx.x;
    if (i >= NNODES) return;
    const float4* ap = (const float4*)(acc + (size_t)i * 20);
    float4 y[4] = {ap[0], ap[1], ap[2], ap[3]};
    float4 S = ap[4];
    float Sv[4] = {S.x, S.y, S.z, S.w};
    float di[4] = {dinv[0], dinv[1], dinv[2], dinv[3]};
    float o[4];
#pragma unroll
    for (int oo = 0; oo < 4; oo++) {
        float a = bo[oo];
#pragma unroll
        for (int h = 0; h < 4; h++) {
            float m = C[100 + h * 16 + oo * 4 + 0] * y[h].x
                    + C[100 + h * 16 + oo * 4 + 1] * y[h].y
                    + C[100 + h * 16 + oo * 4 + 2] * y[h].z
                    + C[100 + h * 16 + oo * 4 + 3] * y[h].w
                    + C[164 + h * 4 + oo] * Sv[h];
            a += di[h] * m;
        }
        o[oo] = a;
    }
    float4 xv = ((const float4*)x)[i];
    float4 ov;
    ov.x = o[0] + xv.x; ov.y = o[1] + xv.y; ov.z = o[2] + xv.z; ov.w = o[3] + xv.w;
    ((float4*)out)[i] = ov;
}

extern "C" void kernel_launch(void* const* d_in, const int* in_sizes, int n_in,
                              void* d_out, int out_size, void* d_ws, size_t ws_size,
                              hipStream_t stream) {
    const float* x = (const float*)d_in[0];
    const int* ei = (const int*)d_in[1];
    const float* Wq = (const float*)d_in[2];
    const float* bq = (const float*)d_in[3];
    const float* Wk = (const float*)d_in[4];
    const float* bk = (const float*)d_in[5];
    const float* Wv = (const float*)d_in[6];
    const float* bv = (const float*)d_in[7];
    const float* Wo = (const float*)d_in[8];
    const float* bo = (const float*)d_in[9];
    float* out = (float*)d_out;

    float* fws = (float*)d_ws;
    float* C = fws;                              // 256 (192 used)
    float* proj = C + 256;                       // 1,000,000
    float* acc = proj + (size_t)NNODES * 20;     // 1,000,000
    float* den = acc + (size_t)NNODES * 20;      // 4
    float* dinv = den + 4;                       // 4 (+8 pad)
    int* binCnt = (int*)(dinv + 12);             // 256
    int* cnt = binCnt + 256;                     // NNODES
    unsigned* binned = (unsigned*)(cnt + NNODES);          // NBINS*BCAP
    unsigned short* perm = (unsigned short*)(binned + (size_t)NBINS * BCAP); // NNODES*CAP

    k_setup<<<2, 256, 0, stream>>>(Wq, bq, Wk, bk, Wv, bv, Wo, C, binCnt, den);
    k_proj<<<(NNODES + 255) / 256, 256, 0, stream>>>(x, C, proj);
    k_binA<<<BIN_BLOCKS, 256, 0, stream>>>(ei, binCnt, binned);
    k_fillB<<<NBINS, 256, 0, stream>>>(binned, binCnt, perm, cnt);
    k_accum<<<(NNODES + 255) / 256, 256, 0, stream>>>(perm, cnt, x, proj, acc, den);
    k_fin<<<1, 64, 0, stream>>>(den, dinv);
    k_out<<<(NNODES + 255) / 256, 256, 0, stream>>>(acc, dinv, C, bo, x, out);
}